// Round 10
// baseline (372.261 us; speedup 1.0000x reference)
//
#include <hip/hip_runtime.h>
#include <math.h>

#define NN 50000
#define NE 800000
#define NEP (NE + NN)   // edges incl self-loops
#define NGRAPH 500
#define NOUT 32
#define NBLK 196        // ceil(NN/256)

typedef _Float16 half4 __attribute__((ext_vector_type(4)));

// ---------------- CSR construction ----------------

__global__ void k_count(const int* __restrict__ dst, int* __restrict__ cnt) {
    int e = blockIdx.x * blockDim.x + threadIdx.x;
    if (e < NE) atomicAdd(&cnt[dst[e]], 1);
}

// pass 1: per-block sums of (cnt[i]+1); also zero pool & cnt_g (pre-k_gat)
__global__ __launch_bounds__(256) void k_scan1(const int* __restrict__ cnt, int* __restrict__ bsum,
                                               float* __restrict__ pool, float* __restrict__ cnt_g) {
    __shared__ int buf[256];
    int gid = blockIdx.x * 256 + threadIdx.x;
    int v = (gid < NN) ? (cnt[gid] + 1) : 0;
    buf[threadIdx.x] = v;
    for (int j = gid; j < NGRAPH * 256; j += NBLK * 256) pool[j] = 0.f;
    if (gid < NGRAPH) cnt_g[gid] = 0.f;
    __syncthreads();
    for (int off = 128; off; off >>= 1) {
        if (threadIdx.x < off) buf[threadIdx.x] += buf[threadIdx.x + off];
        __syncthreads();
    }
    if (threadIdx.x == 0) bsum[blockIdx.x] = buf[0];
}

// pass 2 (fused): every block scans the 196 block sums redundantly, then does
// its intra-block exclusive scan -> row_ptr; also dinv and fill-zeroing.
__global__ __launch_bounds__(256) void k_scan3(const int* __restrict__ cnt,
                                               const int* __restrict__ bsum,
                                               int* __restrict__ row_ptr,
                                               float* __restrict__ dinv,
                                               int* __restrict__ fill) {
    __shared__ int sb[256];
    __shared__ int buf[256];
    int tid = threadIdx.x;
    int bv = (tid < NBLK) ? bsum[tid] : 0;
    sb[tid] = bv;
    __syncthreads();
    for (int off = 1; off < 256; off <<= 1) {
        int t = (tid >= off) ? sb[tid - off] : 0;
        __syncthreads();
        sb[tid] += t;
        __syncthreads();
    }
    int blockoff = (blockIdx.x == 0) ? 0 : sb[blockIdx.x - 1];
    int i = blockIdx.x * 256 + tid;
    int v = (i < NN) ? (cnt[i] + 1) : 0;
    buf[tid] = v;
    __syncthreads();
    for (int off = 1; off < 256; off <<= 1) {
        int t = (tid >= off) ? buf[tid - off] : 0;
        __syncthreads();
        buf[tid] += t;
        __syncthreads();
    }
    if (i < NN) {
        row_ptr[i] = blockoff + buf[tid] - v;
        dinv[i] = rsqrtf((float)(cnt[i] + 1));
        fill[i] = 0;
    }
    if (i == 0) row_ptr[NN] = NEP;
}

__global__ void k_fill(const int* __restrict__ src, const int* __restrict__ dst,
                       const int* __restrict__ row_ptr, int* __restrict__ fill,
                       int* __restrict__ col) {
    int idx = blockIdx.x * blockDim.x + threadIdx.x;
    if (idx < NE) {
        int d = dst[idx];
        int p = row_ptr[d] + atomicAdd(&fill[d], 1);
        col[p] = src[idx];
    } else if (idx < NEP) {
        int i = idx - NE;
        int p = row_ptr[i] + atomicAdd(&fill[i], 1);
        col[p] = i;   // self loop
    }
}

// ---------------- GEMMs ----------------

// hx16[n x 64] (fp16) = x[n x 64] @ W[64 x 64]; block=256, 64 rows/block.
// Inner loop in steps of 4 k: A rows read as broadcast float4 (1 b128 per row
// per 4 k) instead of 4 scalar b32 broadcasts -> ~2x less LDS-pipe time.
__global__ __launch_bounds__(256) void k_gemm64(const float* __restrict__ A,
                                                const float* __restrict__ B,
                                                _Float16* __restrict__ C16, int n) {
    __shared__ float Bs[64 * 64];    // 16 KB
    __shared__ float As[64 * 68];    // 17 KB, stride 68 (68%4==0 -> f4 aligned)
    int tid = threadIdx.x;
    int rb = blockIdx.x * 64;
    for (int i = tid; i < 1024; i += 256) ((float4*)Bs)[i] = ((const float4*)B)[i];
    for (int i = tid; i < 1024; i += 256) {
        int r = i >> 4, c = i & 15;
        int row = rb + r; if (row >= n) row = n - 1;
        ((float4*)As)[r * 17 + c] = ((const float4*)A)[(size_t)row * 16 + c];
    }
    __syncthreads();
    int lane = tid & 63, wv = tid >> 6;
    int fl = lane & 15, sub = lane >> 4;
    int r0 = wv * 16 + sub * 4;
    const float4* Bs4 = (const float4*)Bs;
    float4 acc0 = {0,0,0,0}, acc1 = {0,0,0,0}, acc2 = {0,0,0,0}, acc3 = {0,0,0,0};
#pragma unroll 4
    for (int k4 = 0; k4 < 16; ++k4) {
        float4 b0 = Bs4[(k4 * 4 + 0) * 16 + fl];
        float4 b1 = Bs4[(k4 * 4 + 1) * 16 + fl];
        float4 b2 = Bs4[(k4 * 4 + 2) * 16 + fl];
        float4 b3 = Bs4[(k4 * 4 + 3) * 16 + fl];
        float4 a0 = ((const float4*)(As + (r0 + 0) * 68))[k4];
        float4 a1 = ((const float4*)(As + (r0 + 1) * 68))[k4];
        float4 a2 = ((const float4*)(As + (r0 + 2) * 68))[k4];
        float4 a3 = ((const float4*)(As + (r0 + 3) * 68))[k4];
        acc0.x += a0.x*b0.x + a0.y*b1.x + a0.z*b2.x + a0.w*b3.x;
        acc0.y += a0.x*b0.y + a0.y*b1.y + a0.z*b2.y + a0.w*b3.y;
        acc0.z += a0.x*b0.z + a0.y*b1.z + a0.z*b2.z + a0.w*b3.z;
        acc0.w += a0.x*b0.w + a0.y*b1.w + a0.z*b2.w + a0.w*b3.w;
        acc1.x += a1.x*b0.x + a1.y*b1.x + a1.z*b2.x + a1.w*b3.x;
        acc1.y += a1.x*b0.y + a1.y*b1.y + a1.z*b2.y + a1.w*b3.y;
        acc1.z += a1.x*b0.z + a1.y*b1.z + a1.z*b2.z + a1.w*b3.z;
        acc1.w += a1.x*b0.w + a1.y*b1.w + a1.z*b2.w + a1.w*b3.w;
        acc2.x += a2.x*b0.x + a2.y*b1.x + a2.z*b2.x + a2.w*b3.x;
        acc2.y += a2.x*b0.y + a2.y*b1.y + a2.z*b2.y + a2.w*b3.y;
        acc2.z += a2.x*b0.z + a2.y*b1.z + a2.z*b2.z + a2.w*b3.z;
        acc2.w += a2.x*b0.w + a2.y*b1.w + a2.z*b2.w + a2.w*b3.w;
        acc3.x += a3.x*b0.x + a3.y*b1.x + a3.z*b2.x + a3.w*b3.x;
        acc3.y += a3.x*b0.y + a3.y*b1.y + a3.z*b2.y + a3.w*b3.y;
        acc3.z += a3.x*b0.z + a3.y*b1.z + a3.z*b2.z + a3.w*b3.z;
        acc3.w += a3.x*b0.w + a3.y*b1.w + a3.z*b2.w + a3.w*b3.w;
    }
    int row = rb + r0;
    half4 h0, h1, h2, h3;
    h0.x=(_Float16)acc0.x; h0.y=(_Float16)acc0.y; h0.z=(_Float16)acc0.z; h0.w=(_Float16)acc0.w;
    h1.x=(_Float16)acc1.x; h1.y=(_Float16)acc1.y; h1.z=(_Float16)acc1.z; h1.w=(_Float16)acc1.w;
    h2.x=(_Float16)acc2.x; h2.y=(_Float16)acc2.y; h2.z=(_Float16)acc2.z; h2.w=(_Float16)acc2.w;
    h3.x=(_Float16)acc3.x; h3.y=(_Float16)acc3.y; h3.z=(_Float16)acc3.z; h3.w=(_Float16)acc3.w;
    if (row + 0 < n) ((half4*)(C16 + (size_t)(row + 0) * 64))[fl] = h0;
    if (row + 1 < n) ((half4*)(C16 + (size_t)(row + 1) * 64))[fl] = h1;
    if (row + 2 < n) ((half4*)(C16 + (size_t)(row + 2) * 64))[fl] = h2;
    if (row + 3 < n) ((half4*)(C16 + (size_t)(row + 3) * 64))[fl] = h3;
}

// g16[n x 256] (fp16) = h16[n x 64] @ W[64 x 256] + fused attention logits (fp32).
// Inner loop in steps of 4 k: A rows read as broadcast float4 (8 b128 per 4 k)
// instead of 32 scalar b32 broadcasts.
__global__ __launch_bounds__(256) void k_gemm256(const _Float16* __restrict__ A16,
                                                 const float* __restrict__ B,
                                                 const float* __restrict__ att_src,
                                                 const float* __restrict__ att_dst,
                                                 _Float16* __restrict__ g16,
                                                 float* __restrict__ a_s,
                                                 float* __restrict__ a_d) {
    __shared__ float Bs[64 * 256];   // 64 KB
    __shared__ float As[32 * 64];    // 8 KB
    int tid = threadIdx.x;
    int rb = blockIdx.x * 32;
    for (int i = tid; i < 4096; i += 256) ((float4*)Bs)[i] = ((const float4*)B)[i];
    for (int i = tid; i < 512; i += 256) {
        int r = i >> 4, c = i & 15;
        int row = rb + r; if (row >= NN) row = NN - 1;
        half4 hv = ((const half4*)A16)[(size_t)row * 16 + c];
        float4 f;
        f.x = (float)hv.x; f.y = (float)hv.y; f.z = (float)hv.z; f.w = (float)hv.w;
        ((float4*)As)[i] = f;
    }
    __syncthreads();
    int lane = tid & 63, wv = tid >> 6;
    const float4* Bs4 = (const float4*)Bs;
    float4 as4 = ((const float4*)att_src)[lane];
    float4 ad4 = ((const float4*)att_dst)[lane];
    const float* Aw = As + (wv * 8) * 64;
    float4 acc[8];
#pragma unroll
    for (int r = 0; r < 8; ++r) acc[r] = make_float4(0.f, 0.f, 0.f, 0.f);
#pragma unroll 2
    for (int k4 = 0; k4 < 16; ++k4) {
        float4 b0 = Bs4[(k4 * 4 + 0) * 64 + lane];
        float4 b1 = Bs4[(k4 * 4 + 1) * 64 + lane];
        float4 b2 = Bs4[(k4 * 4 + 2) * 64 + lane];
        float4 b3 = Bs4[(k4 * 4 + 3) * 64 + lane];
#pragma unroll
        for (int r = 0; r < 8; ++r) {
            float4 a4 = ((const float4*)(Aw + r * 64))[k4];
            acc[r].x += a4.x*b0.x + a4.y*b1.x + a4.z*b2.x + a4.w*b3.x;
            acc[r].y += a4.x*b0.y + a4.y*b1.y + a4.z*b2.y + a4.w*b3.y;
            acc[r].z += a4.x*b0.z + a4.y*b1.z + a4.z*b2.z + a4.w*b3.z;
            acc[r].w += a4.x*b0.w + a4.y*b1.w + a4.z*b2.w + a4.w*b3.w;
        }
    }
#pragma unroll
    for (int r = 0; r < 8; ++r) {
        int row = rb + wv * 8 + r;
        bool valid = row < NN;   // wave-uniform
        if (valid) {
            half4 hv;
            hv.x = (_Float16)acc[r].x; hv.y = (_Float16)acc[r].y;
            hv.z = (_Float16)acc[r].z; hv.w = (_Float16)acc[r].w;
            ((half4*)(g16 + (size_t)row * 256))[lane] = hv;
        }
        float vs = acc[r].x * as4.x + acc[r].y * as4.y + acc[r].z * as4.z + acc[r].w * as4.w;
        float vd = acc[r].x * ad4.x + acc[r].y * ad4.y + acc[r].z * ad4.z + acc[r].w * ad4.w;
#pragma unroll
        for (int off = 1; off < 16; off <<= 1) {
            vs += __shfl_xor(vs, off);
            vd += __shfl_xor(vd, off);
        }
        if (valid && (lane & 15) == 0) {
            a_s[row * 4 + (lane >> 4)] = vs;
            a_d[row * 4 + (lane >> 4)] = vd;
        }
    }
}

// ---------------- GCN aggregation: fp16 gather, 8 edges in flight ----------------

__global__ __launch_bounds__(256) void k_gcn_agg(const _Float16* __restrict__ hx16,
                                                 const int* __restrict__ row_ptr,
                                                 const int* __restrict__ col,
                                                 const float* __restrict__ dinv,
                                                 const float* __restrict__ bias,
                                                 _Float16* __restrict__ h16) {
    int wid = (blockIdx.x * blockDim.x + threadIdx.x) >> 6;
    int lane = threadIdx.x & 63;
    if (wid >= NN) return;
    int sub = lane >> 4;    // edge slot within 4-group
    int fl  = lane & 15;    // half4 index within row
    int s0 = row_ptr[wid], s1 = row_ptr[wid + 1];
    float di = dinv[wid];
    const half4* hx4 = (const half4*)hx16;
    float ax = 0.f, ay = 0.f, az = 0.f, aw = 0.f;
    int k = s0 + sub;
    for (; k + 4 < s1; k += 8) {
        int sA = col[k], sB = col[k + 4];
        float wA = dinv[sA] * di, wB = dinv[sB] * di;
        half4 vA = hx4[(size_t)sA * 16 + fl];
        half4 vB = hx4[(size_t)sB * 16 + fl];
        ax += wA * (float)vA.x + wB * (float)vB.x;
        ay += wA * (float)vA.y + wB * (float)vB.y;
        az += wA * (float)vA.z + wB * (float)vB.z;
        aw += wA * (float)vA.w + wB * (float)vB.w;
    }
    if (k < s1) {
        int s = col[k];
        float w = dinv[s] * di;
        half4 v = hx4[(size_t)s * 16 + fl];
        ax += w * (float)v.x; ay += w * (float)v.y;
        az += w * (float)v.z; aw += w * (float)v.w;
    }
    ax += __shfl_xor(ax, 16); ax += __shfl_xor(ax, 32);
    ay += __shfl_xor(ay, 16); ay += __shfl_xor(ay, 32);
    az += __shfl_xor(az, 16); az += __shfl_xor(az, 32);
    aw += __shfl_xor(aw, 16); aw += __shfl_xor(aw, 32);
    if (sub == 0) {
        float4 bb = ((const float4*)bias)[fl];
        half4 z;
        z.x = (_Float16)fmaxf(ax + bb.x, 0.f);
        z.y = (_Float16)fmaxf(ay + bb.y, 0.f);
        z.z = (_Float16)fmaxf(az + bb.z, 0.f);
        z.w = (_Float16)fmaxf(aw + bb.w, 0.f);
        ((half4*)(h16 + (size_t)wid * 64))[fl] = z;
    }
}

// ---------------- GAT: single-pass online softmax, fp16 half4 gather ----------------

__device__ __forceinline__ float lrelu(float x) { return x > 0.f ? x : 0.2f * x; }

__global__ __launch_bounds__(256) void k_gat(const _Float16* __restrict__ g16,
                                             const float* __restrict__ a_s,
                                             const float* __restrict__ a_d,
                                             const int* __restrict__ row_ptr,
                                             const int* __restrict__ col,
                                             const float* __restrict__ gat_b,
                                             const int* __restrict__ batch,
                                             float* __restrict__ pool,
                                             float* __restrict__ cnt_g) {
    __shared__ float zpool[256];
    __shared__ int bids[4];
    int tid = threadIdx.x;
    int wv = tid >> 6, lane = tid & 63;
    int wid = blockIdx.x * 4 + wv;           // NN == gridDim.x*4, always valid
    int hh = lane >> 4;                      // head owned by this lane

    int s0 = row_ptr[wid], s1 = row_ptr[wid + 1];
    float adsel = a_d[wid * 4 + hh];
    const half4* gv4 = (const half4*)g16;

    float m = -1e30f, t = 0.f;
    float ax = 0.f, ay = 0.f, az = 0.f, aw = 0.f;

    int k = s0;
    for (; k + 7 < s1; k += 8) {
        int i0 = col[k], i1 = col[k + 1], i2 = col[k + 2], i3 = col[k + 3];
        int i4 = col[k + 4], i5 = col[k + 5], i6 = col[k + 6], i7 = col[k + 7];
        float e0 = lrelu(a_s[i0 * 4 + hh] + adsel);
        float e1 = lrelu(a_s[i1 * 4 + hh] + adsel);
        float e2 = lrelu(a_s[i2 * 4 + hh] + adsel);
        float e3 = lrelu(a_s[i3 * 4 + hh] + adsel);
        float e4 = lrelu(a_s[i4 * 4 + hh] + adsel);
        float e5 = lrelu(a_s[i5 * 4 + hh] + adsel);
        float e6 = lrelu(a_s[i6 * 4 + hh] + adsel);
        float e7 = lrelu(a_s[i7 * 4 + hh] + adsel);
        half4 g0 = gv4[(size_t)i0 * 64 + lane];
        half4 g1 = gv4[(size_t)i1 * 64 + lane];
        half4 g2 = gv4[(size_t)i2 * 64 + lane];
        half4 g3 = gv4[(size_t)i3 * 64 + lane];
        half4 g4v = gv4[(size_t)i4 * 64 + lane];
        half4 g5v = gv4[(size_t)i5 * 64 + lane];
        half4 g6 = gv4[(size_t)i6 * 64 + lane];
        half4 g7 = gv4[(size_t)i7 * 64 + lane];
        float mn = fmaxf(fmaxf(fmaxf(e0, e1), fmaxf(e2, e3)),
                         fmaxf(fmaxf(e4, e5), fmaxf(e6, e7)));
        mn = fmaxf(mn, m);
        float c = __expf(m - mn);
        float w0 = __expf(e0 - mn), w1 = __expf(e1 - mn);
        float w2 = __expf(e2 - mn), w3 = __expf(e3 - mn);
        float w4 = __expf(e4 - mn), w5 = __expf(e5 - mn);
        float w6 = __expf(e6 - mn), w7 = __expf(e7 - mn);
        t = t * c + ((w0 + w1) + (w2 + w3)) + ((w4 + w5) + (w6 + w7));
        ax = ax * c + w0 * (float)g0.x + w1 * (float)g1.x + w2 * (float)g2.x + w3 * (float)g3.x
                    + w4 * (float)g4v.x + w5 * (float)g5v.x + w6 * (float)g6.x + w7 * (float)g7.x;
        ay = ay * c + w0 * (float)g0.y + w1 * (float)g1.y + w2 * (float)g2.y + w3 * (float)g3.y
                    + w4 * (float)g4v.y + w5 * (float)g5v.y + w6 * (float)g6.y + w7 * (float)g7.y;
        az = az * c + w0 * (float)g0.z + w1 * (float)g1.z + w2 * (float)g2.z + w3 * (float)g3.z
                    + w4 * (float)g4v.z + w5 * (float)g5v.z + w6 * (float)g6.z + w7 * (float)g7.z;
        aw = aw * c + w0 * (float)g0.w + w1 * (float)g1.w + w2 * (float)g2.w + w3 * (float)g3.w
                    + w4 * (float)g4v.w + w5 * (float)g5v.w + w6 * (float)g6.w + w7 * (float)g7.w;
        m = mn;
    }
    for (; k + 3 < s1; k += 4) {
        int i0 = col[k], i1 = col[k + 1], i2 = col[k + 2], i3 = col[k + 3];
        float e0 = lrelu(a_s[i0 * 4 + hh] + adsel);
        float e1 = lrelu(a_s[i1 * 4 + hh] + adsel);
        float e2 = lrelu(a_s[i2 * 4 + hh] + adsel);
        float e3 = lrelu(a_s[i3 * 4 + hh] + adsel);
        half4 g0 = gv4[(size_t)i0 * 64 + lane];
        half4 g1 = gv4[(size_t)i1 * 64 + lane];
        half4 g2 = gv4[(size_t)i2 * 64 + lane];
        half4 g3 = gv4[(size_t)i3 * 64 + lane];
        float mn = fmaxf(fmaxf(fmaxf(e0, e1), fmaxf(e2, e3)), m);
        float c = __expf(m - mn);
        float w0 = __expf(e0 - mn), w1 = __expf(e1 - mn);
        float w2 = __expf(e2 - mn), w3 = __expf(e3 - mn);
        t = t * c + (w0 + w1) + (w2 + w3);
        ax = ax * c + w0 * (float)g0.x + w1 * (float)g1.x + w2 * (float)g2.x + w3 * (float)g3.x;
        ay = ay * c + w0 * (float)g0.y + w1 * (float)g1.y + w2 * (float)g2.y + w3 * (float)g3.y;
        az = az * c + w0 * (float)g0.z + w1 * (float)g1.z + w2 * (float)g2.z + w3 * (float)g3.z;
        aw = aw * c + w0 * (float)g0.w + w1 * (float)g1.w + w2 * (float)g2.w + w3 * (float)g3.w;
        m = mn;
    }
    for (; k < s1; ++k) {
        int s = col[k];
        float e = lrelu(a_s[s * 4 + hh] + adsel);
        half4 gv = gv4[(size_t)s * 64 + lane];
        float mn = fmaxf(m, e);
        float c = __expf(m - mn);
        float w = __expf(e - mn);
        t = t * c + w;
        ax = ax * c + w * (float)gv.x;
        ay = ay * c + w * (float)gv.y;
        az = az * c + w * (float)gv.z;
        aw = aw * c + w * (float)gv.w;
        m = mn;
    }
    float r = 1.f / t;

    float4 gb = ((const float4*)gat_b)[lane];
    float zx = fmaxf(ax * r + gb.x, 0.f);
    float zy = fmaxf(ay * r + gb.y, 0.f);
    float zz = fmaxf(az * r + gb.z, 0.f);
    float zw = fmaxf(aw * r + gb.w, 0.f);

    int b = batch[wid];
    if (lane == 0) bids[wv] = b;
    zpool[tid] = 0.f;
    __syncthreads();
    bool uni = (bids[0] == bids[1]) && (bids[1] == bids[2]) && (bids[2] == bids[3]);
    if (uni) {
        atomicAdd(&zpool[lane * 4 + 0], zx);
        atomicAdd(&zpool[lane * 4 + 1], zy);
        atomicAdd(&zpool[lane * 4 + 2], zz);
        atomicAdd(&zpool[lane * 4 + 3], zw);
        __syncthreads();
        if (wv == 0) {
            float* p = pool + (size_t)bids[0] * 256;
            atomicAdd(&p[lane * 4 + 0], zpool[lane * 4 + 0]);
            atomicAdd(&p[lane * 4 + 1], zpool[lane * 4 + 1]);
            atomicAdd(&p[lane * 4 + 2], zpool[lane * 4 + 2]);
            atomicAdd(&p[lane * 4 + 3], zpool[lane * 4 + 3]);
        }
        if (tid == 0) atomicAdd(&cnt_g[bids[0]], 4.0f);
    } else {
        __syncthreads();
        float* p = pool + (size_t)b * 256;
        atomicAdd(&p[lane * 4 + 0], zx);
        atomicAdd(&p[lane * 4 + 1], zy);
        atomicAdd(&p[lane * 4 + 2], zz);
        atomicAdd(&p[lane * 4 + 3], zw);
        if (lane == 0) atomicAdd(&cnt_g[b], 1.0f);
    }
}

// ---------------- output projection ----------------

__global__ void k_out(const float* __restrict__ pool, const float* __restrict__ cnt_g,
                      const float* __restrict__ W, const float* __restrict__ b,
                      float* __restrict__ out) {
    int idx = blockIdx.x * blockDim.x + threadIdx.x;
    if (idx >= NGRAPH * NOUT) return;
    int gg = idx >> 5, o = idx & 31;
    float c = cnt_g[gg];
    c = c > 1.f ? c : 1.f;
    float rinv = 1.f / c;
    const float* p = pool + (size_t)gg * 256;
    float acc = 0.f;
#pragma unroll 8
    for (int f = 0; f < 256; ++f) acc += p[f] * W[f * 32 + o];
    out[idx] = acc * rinv + b[o];
}

// ---------------- launch ----------------

extern "C" void kernel_launch(void* const* d_in, const int* in_sizes, int n_in,
                              void* d_out, int out_size, void* d_ws, size_t ws_size,
                              hipStream_t stream) {
    const float* x       = (const float*)d_in[0];
    const int*   eidx    = (const int*)d_in[1];
    const int*   batch   = (const int*)d_in[2];
    const float* gcn_W   = (const float*)d_in[3];
    const float* gcn_b   = (const float*)d_in[4];
    const float* gat_W   = (const float*)d_in[5];
    const float* att_src = (const float*)d_in[6];
    const float* att_dst = (const float*)d_in[7];
    const float* gat_b   = (const float*)d_in[8];
    const float* out_W   = (const float*)d_in[9];
    const float* out_b   = (const float*)d_in[10];
    float* out = (float*)d_out;

    const int* src = eidx;        // edge_index[0]
    const int* dst = eidx + NE;   // edge_index[1]

    size_t off = 0;
    auto carve = [&](size_t bytes) -> char* {
        char* p = (char*)d_ws + off;
        off += (bytes + 255) & ~(size_t)255;
        return p;
    };
    int*      cnt     = (int*)carve(NN * sizeof(int));
    int*      fill    = (int*)carve(NN * sizeof(int));
    int*      row_ptr = (int*)carve((NN + 1) * sizeof(int));
    int*      bsum    = (int*)carve(256 * sizeof(int));
    int*      colb    = (int*)carve((size_t)NEP * sizeof(int));
    float*    dinv    = (float*)carve(NN * sizeof(float));
    _Float16* hx16    = (_Float16*)carve((size_t)NN * 64 * sizeof(_Float16));
    _Float16* h16     = (_Float16*)carve((size_t)NN * 64 * sizeof(_Float16));
    _Float16* g16     = (_Float16*)carve((size_t)NN * 256 * sizeof(_Float16));
    float*    a_s     = (float*)carve((size_t)NN * 4 * sizeof(float));
    float*    a_d     = (float*)carve((size_t)NN * 4 * sizeof(float));
    float*    pool    = (float*)carve((size_t)NGRAPH * 256 * sizeof(float));
    float*    cnt_g   = (float*)carve(NGRAPH * sizeof(float));

    hipMemsetAsync(cnt, 0, NN * sizeof(int), stream);

    // CSR build (R5-measured structure)
    k_count<<<(NE + 255) / 256, 256, 0, stream>>>(dst, cnt);
    k_scan1<<<NBLK, 256, 0, stream>>>(cnt, bsum, pool, cnt_g);
    k_scan3<<<NBLK, 256, 0, stream>>>(cnt, bsum, row_ptr, dinv, fill);
    k_fill<<<(NEP + 255) / 256, 256, 0, stream>>>(src, dst, row_ptr, fill, colb);

    // GCN
    k_gemm64<<<(NN + 63) / 64, 256, 0, stream>>>(x, gcn_W, hx16, NN);
    k_gcn_agg<<<(NN * 64 + 255) / 256, 256, 0, stream>>>(hx16, row_ptr, colb, dinv, gcn_b, h16);

    // GAT (gemm + fused logits -> fp16 g, then single-pass online softmax agg)
    k_gemm256<<<(NN + 31) / 32, 256, 0, stream>>>(h16, gat_W, att_src, att_dst, g16, a_s, a_d);
    k_gat<<<NN / 4, 256, 0, stream>>>(g16, a_s, a_d, row_ptr, colb, gat_b, batch, pool, cnt_g);

    // output projection
    k_out<<<(NGRAPH * NOUT + 255) / 256, 256, 0, stream>>>(pool, cnt_g, out_W, out_b, out);
}

// Round 11
// 344.960 us; speedup vs baseline: 1.0791x; 1.0791x over previous
//
#include <hip/hip_runtime.h>
#include <math.h>

#define NN 50000
#define NE 800000
#define NEP (NE + NN)   // edges incl self-loops
#define NGRAPH 500
#define NOUT 32
#define NBLK 196        // ceil(NN/256)

typedef _Float16 half4 __attribute__((ext_vector_type(4)));

// ---------------- CSR construction ----------------

// count in-degree AND record each edge's slot within its dst row (atomic's old value)
__global__ void k_count(const int* __restrict__ dst, int* __restrict__ cnt,
                        int* __restrict__ pos) {
    int e = blockIdx.x * blockDim.x + threadIdx.x;
    if (e < NE) pos[e] = atomicAdd(&cnt[dst[e]], 1);
}

// pass 1: per-block sums of (cnt[i]+1); also zero pool & cnt_g (pre-k_gat)
__global__ __launch_bounds__(256) void k_scan1(const int* __restrict__ cnt, int* __restrict__ bsum,
                                               float* __restrict__ pool, float* __restrict__ cnt_g) {
    __shared__ int buf[256];
    int gid = blockIdx.x * 256 + threadIdx.x;
    int v = (gid < NN) ? (cnt[gid] + 1) : 0;
    buf[threadIdx.x] = v;
    for (int j = gid; j < NGRAPH * 256; j += NBLK * 256) pool[j] = 0.f;
    if (gid < NGRAPH) cnt_g[gid] = 0.f;
    __syncthreads();
    for (int off = 128; off; off >>= 1) {
        if (threadIdx.x < off) buf[threadIdx.x] += buf[threadIdx.x + off];
        __syncthreads();
    }
    if (threadIdx.x == 0) bsum[blockIdx.x] = buf[0];
}

// pass 2 (fused): every block scans the 196 block sums redundantly, then does
// its intra-block exclusive scan -> row_ptr; also dinv and self-loop at slot 0.
__global__ __launch_bounds__(256) void k_scan3(const int* __restrict__ cnt,
                                               const int* __restrict__ bsum,
                                               int* __restrict__ row_ptr,
                                               float* __restrict__ dinv,
                                               int* __restrict__ col) {
    __shared__ int sb[256];
    __shared__ int buf[256];
    int tid = threadIdx.x;
    int bv = (tid < NBLK) ? bsum[tid] : 0;
    sb[tid] = bv;
    __syncthreads();
    for (int off = 1; off < 256; off <<= 1) {
        int t = (tid >= off) ? sb[tid - off] : 0;
        __syncthreads();
        sb[tid] += t;
        __syncthreads();
    }
    int blockoff = (blockIdx.x == 0) ? 0 : sb[blockIdx.x - 1];
    int i = blockIdx.x * 256 + tid;
    int v = (i < NN) ? (cnt[i] + 1) : 0;
    buf[tid] = v;
    __syncthreads();
    for (int off = 1; off < 256; off <<= 1) {
        int t = (tid >= off) ? buf[tid - off] : 0;
        __syncthreads();
        buf[tid] += t;
        __syncthreads();
    }
    if (i < NN) {
        int rp = blockoff + buf[tid] - v;
        row_ptr[i] = rp;
        dinv[i] = rsqrtf((float)(cnt[i] + 1));
        col[rp] = i;   // self-loop occupies slot 0 of each row
    }
    if (i == 0) row_ptr[NN] = NEP;
}

// real edges at slot 1 + pos[e]: pure scattered write, NO atomics
__global__ void k_fill(const int* __restrict__ src, const int* __restrict__ dst,
                       const int* __restrict__ row_ptr, const int* __restrict__ pos,
                       int* __restrict__ col) {
    int idx = blockIdx.x * blockDim.x + threadIdx.x;
    if (idx < NE) {
        int d = dst[idx];
        col[row_ptr[d] + 1 + pos[idx]] = src[idx];
    }
}

// ---------------- GEMMs (R8-measured config) ----------------

// hx16[n x 64] (fp16) = x[n x 64] @ W[64 x 64]; block=256, 64 rows/block.
__global__ __launch_bounds__(256) void k_gemm64(const float* __restrict__ A,
                                                const float* __restrict__ B,
                                                _Float16* __restrict__ C16, int n) {
    __shared__ float Bs[64 * 64];    // 16 KB
    __shared__ float As[64 * 68];    // 17 KB, stride 68
    int tid = threadIdx.x;
    int rb = blockIdx.x * 64;
    for (int i = tid; i < 1024; i += 256) ((float4*)Bs)[i] = ((const float4*)B)[i];
    for (int i = tid; i < 1024; i += 256) {
        int r = i >> 4, c = i & 15;
        int row = rb + r; if (row >= n) row = n - 1;
        ((float4*)As)[r * 17 + c] = ((const float4*)A)[(size_t)row * 16 + c];
    }
    __syncthreads();
    int lane = tid & 63, wv = tid >> 6;
    int fl = lane & 15, sub = lane >> 4;
    int r0 = wv * 16 + sub * 4;
    const float4* Bs4 = (const float4*)Bs;
    float4 acc0 = {0,0,0,0}, acc1 = {0,0,0,0}, acc2 = {0,0,0,0}, acc3 = {0,0,0,0};
#pragma unroll 4
    for (int k = 0; k < 64; ++k) {
        float4 b4 = Bs4[k * 16 + fl];
        float a0 = As[(r0 + 0) * 68 + k];
        float a1 = As[(r0 + 1) * 68 + k];
        float a2 = As[(r0 + 2) * 68 + k];
        float a3 = As[(r0 + 3) * 68 + k];
        acc0.x += a0 * b4.x; acc0.y += a0 * b4.y; acc0.z += a0 * b4.z; acc0.w += a0 * b4.w;
        acc1.x += a1 * b4.x; acc1.y += a1 * b4.y; acc1.z += a1 * b4.z; acc1.w += a1 * b4.w;
        acc2.x += a2 * b4.x; acc2.y += a2 * b4.y; acc2.z += a2 * b4.z; acc2.w += a2 * b4.w;
        acc3.x += a3 * b4.x; acc3.y += a3 * b4.y; acc3.z += a3 * b4.z; acc3.w += a3 * b4.w;
    }
    int row = rb + r0;
    half4 h0, h1, h2, h3;
    h0.x=(_Float16)acc0.x; h0.y=(_Float16)acc0.y; h0.z=(_Float16)acc0.z; h0.w=(_Float16)acc0.w;
    h1.x=(_Float16)acc1.x; h1.y=(_Float16)acc1.y; h1.z=(_Float16)acc1.z; h1.w=(_Float16)acc1.w;
    h2.x=(_Float16)acc2.x; h2.y=(_Float16)acc2.y; h2.z=(_Float16)acc2.z; h2.w=(_Float16)acc2.w;
    h3.x=(_Float16)acc3.x; h3.y=(_Float16)acc3.y; h3.z=(_Float16)acc3.z; h3.w=(_Float16)acc3.w;
    if (row + 0 < n) ((half4*)(C16 + (size_t)(row + 0) * 64))[fl] = h0;
    if (row + 1 < n) ((half4*)(C16 + (size_t)(row + 1) * 64))[fl] = h1;
    if (row + 2 < n) ((half4*)(C16 + (size_t)(row + 2) * 64))[fl] = h2;
    if (row + 3 < n) ((half4*)(C16 + (size_t)(row + 3) * 64))[fl] = h3;
}

// g16[n x 256] (fp16) = h16[n x 64] @ W[64 x 256] + fused attention logits (fp32).
__global__ __launch_bounds__(256) void k_gemm256(const _Float16* __restrict__ A16,
                                                 const float* __restrict__ B,
                                                 const float* __restrict__ att_src,
                                                 const float* __restrict__ att_dst,
                                                 _Float16* __restrict__ g16,
                                                 float* __restrict__ a_s,
                                                 float* __restrict__ a_d) {
    __shared__ float Bs[64 * 256];   // 64 KB
    __shared__ float As[32 * 64];    // 8 KB
    int tid = threadIdx.x;
    int rb = blockIdx.x * 32;
    for (int i = tid; i < 4096; i += 256) ((float4*)Bs)[i] = ((const float4*)B)[i];
    for (int i = tid; i < 512; i += 256) {
        int r = i >> 4, c = i & 15;
        int row = rb + r; if (row >= NN) row = NN - 1;
        half4 hv = ((const half4*)A16)[(size_t)row * 16 + c];
        float4 f;
        f.x = (float)hv.x; f.y = (float)hv.y; f.z = (float)hv.z; f.w = (float)hv.w;
        ((float4*)As)[i] = f;
    }
    __syncthreads();
    int lane = tid & 63, wv = tid >> 6;
    const float4* Bs4 = (const float4*)Bs;
    float4 as4 = ((const float4*)att_src)[lane];
    float4 ad4 = ((const float4*)att_dst)[lane];
    const float* Aw = As + (wv * 8) * 64;
    float4 acc[8];
#pragma unroll
    for (int r = 0; r < 8; ++r) acc[r] = make_float4(0.f, 0.f, 0.f, 0.f);
#pragma unroll 4
    for (int k = 0; k < 64; ++k) {
        float4 b4 = Bs4[k * 64 + lane];
#pragma unroll
        for (int r = 0; r < 8; ++r) {
            float av = Aw[r * 64 + k];
            acc[r].x += av * b4.x; acc[r].y += av * b4.y;
            acc[r].z += av * b4.z; acc[r].w += av * b4.w;
        }
    }
#pragma unroll
    for (int r = 0; r < 8; ++r) {
        int row = rb + wv * 8 + r;
        bool valid = row < NN;   // wave-uniform
        if (valid) {
            half4 hv;
            hv.x = (_Float16)acc[r].x; hv.y = (_Float16)acc[r].y;
            hv.z = (_Float16)acc[r].z; hv.w = (_Float16)acc[r].w;
            ((half4*)(g16 + (size_t)row * 256))[lane] = hv;
        }
        float vs = acc[r].x * as4.x + acc[r].y * as4.y + acc[r].z * as4.z + acc[r].w * as4.w;
        float vd = acc[r].x * ad4.x + acc[r].y * ad4.y + acc[r].z * ad4.z + acc[r].w * ad4.w;
#pragma unroll
        for (int off = 1; off < 16; off <<= 1) {
            vs += __shfl_xor(vs, off);
            vd += __shfl_xor(vd, off);
        }
        if (valid && (lane & 15) == 0) {
            a_s[row * 4 + (lane >> 4)] = vs;
            a_d[row * 4 + (lane >> 4)] = vd;
        }
    }
}

// ---------------- GCN aggregation: fp16 gather, 8 edges in flight ----------------

__global__ __launch_bounds__(256) void k_gcn_agg(const _Float16* __restrict__ hx16,
                                                 const int* __restrict__ row_ptr,
                                                 const int* __restrict__ col,
                                                 const float* __restrict__ dinv,
                                                 const float* __restrict__ bias,
                                                 _Float16* __restrict__ h16) {
    int wid = (blockIdx.x * blockDim.x + threadIdx.x) >> 6;
    int lane = threadIdx.x & 63;
    if (wid >= NN) return;
    int sub = lane >> 4;    // edge slot within 4-group
    int fl  = lane & 15;    // half4 index within row
    int s0 = row_ptr[wid], s1 = row_ptr[wid + 1];
    float di = dinv[wid];
    const half4* hx4 = (const half4*)hx16;
    float ax = 0.f, ay = 0.f, az = 0.f, aw = 0.f;
    int k = s0 + sub;
    for (; k + 4 < s1; k += 8) {
        int sA = col[k], sB = col[k + 4];
        float wA = dinv[sA] * di, wB = dinv[sB] * di;
        half4 vA = hx4[(size_t)sA * 16 + fl];
        half4 vB = hx4[(size_t)sB * 16 + fl];
        ax += wA * (float)vA.x + wB * (float)vB.x;
        ay += wA * (float)vA.y + wB * (float)vB.y;
        az += wA * (float)vA.z + wB * (float)vB.z;
        aw += wA * (float)vA.w + wB * (float)vB.w;
    }
    if (k < s1) {
        int s = col[k];
        float w = dinv[s] * di;
        half4 v = hx4[(size_t)s * 16 + fl];
        ax += w * (float)v.x; ay += w * (float)v.y;
        az += w * (float)v.z; aw += w * (float)v.w;
    }
    ax += __shfl_xor(ax, 16); ax += __shfl_xor(ax, 32);
    ay += __shfl_xor(ay, 16); ay += __shfl_xor(ay, 32);
    az += __shfl_xor(az, 16); az += __shfl_xor(az, 32);
    aw += __shfl_xor(aw, 16); aw += __shfl_xor(aw, 32);
    if (sub == 0) {
        float4 bb = ((const float4*)bias)[fl];
        half4 z;
        z.x = (_Float16)fmaxf(ax + bb.x, 0.f);
        z.y = (_Float16)fmaxf(ay + bb.y, 0.f);
        z.z = (_Float16)fmaxf(az + bb.z, 0.f);
        z.w = (_Float16)fmaxf(aw + bb.w, 0.f);
        ((half4*)(h16 + (size_t)wid * 64))[fl] = z;
    }
}

// ---------------- GAT: single-pass online softmax, fp16 half4 gather ----------------

__device__ __forceinline__ float lrelu(float x) { return x > 0.f ? x : 0.2f * x; }

__global__ __launch_bounds__(256) void k_gat(const _Float16* __restrict__ g16,
                                             const float* __restrict__ a_s,
                                             const float* __restrict__ a_d,
                                             const int* __restrict__ row_ptr,
                                             const int* __restrict__ col,
                                             const float* __restrict__ gat_b,
                                             const int* __restrict__ batch,
                                             float* __restrict__ pool,
                                             float* __restrict__ cnt_g) {
    __shared__ float zpool[256];
    __shared__ int bids[4];
    int tid = threadIdx.x;
    int wv = tid >> 6, lane = tid & 63;
    int wid = blockIdx.x * 4 + wv;           // NN == gridDim.x*4, always valid
    int hh = lane >> 4;                      // head owned by this lane

    int s0 = row_ptr[wid], s1 = row_ptr[wid + 1];
    float adsel = a_d[wid * 4 + hh];
    const half4* gv4 = (const half4*)g16;

    float m = -1e30f, t = 0.f;
    float ax = 0.f, ay = 0.f, az = 0.f, aw = 0.f;

    int k = s0;
    for (; k + 7 < s1; k += 8) {
        int i0 = col[k], i1 = col[k + 1], i2 = col[k + 2], i3 = col[k + 3];
        int i4 = col[k + 4], i5 = col[k + 5], i6 = col[k + 6], i7 = col[k + 7];
        float e0 = lrelu(a_s[i0 * 4 + hh] + adsel);
        float e1 = lrelu(a_s[i1 * 4 + hh] + adsel);
        float e2 = lrelu(a_s[i2 * 4 + hh] + adsel);
        float e3 = lrelu(a_s[i3 * 4 + hh] + adsel);
        float e4 = lrelu(a_s[i4 * 4 + hh] + adsel);
        float e5 = lrelu(a_s[i5 * 4 + hh] + adsel);
        float e6 = lrelu(a_s[i6 * 4 + hh] + adsel);
        float e7 = lrelu(a_s[i7 * 4 + hh] + adsel);
        half4 g0 = gv4[(size_t)i0 * 64 + lane];
        half4 g1 = gv4[(size_t)i1 * 64 + lane];
        half4 g2 = gv4[(size_t)i2 * 64 + lane];
        half4 g3 = gv4[(size_t)i3 * 64 + lane];
        half4 g4v = gv4[(size_t)i4 * 64 + lane];
        half4 g5v = gv4[(size_t)i5 * 64 + lane];
        half4 g6 = gv4[(size_t)i6 * 64 + lane];
        half4 g7 = gv4[(size_t)i7 * 64 + lane];
        float mn = fmaxf(fmaxf(fmaxf(e0, e1), fmaxf(e2, e3)),
                         fmaxf(fmaxf(e4, e5), fmaxf(e6, e7)));
        mn = fmaxf(mn, m);
        float c = __expf(m - mn);
        float w0 = __expf(e0 - mn), w1 = __expf(e1 - mn);
        float w2 = __expf(e2 - mn), w3 = __expf(e3 - mn);
        float w4 = __expf(e4 - mn), w5 = __expf(e5 - mn);
        float w6 = __expf(e6 - mn), w7 = __expf(e7 - mn);
        t = t * c + ((w0 + w1) + (w2 + w3)) + ((w4 + w5) + (w6 + w7));
        ax = ax * c + w0 * (float)g0.x + w1 * (float)g1.x + w2 * (float)g2.x + w3 * (float)g3.x
                    + w4 * (float)g4v.x + w5 * (float)g5v.x + w6 * (float)g6.x + w7 * (float)g7.x;
        ay = ay * c + w0 * (float)g0.y + w1 * (float)g1.y + w2 * (float)g2.y + w3 * (float)g3.y
                    + w4 * (float)g4v.y + w5 * (float)g5v.y + w6 * (float)g6.y + w7 * (float)g7.y;
        az = az * c + w0 * (float)g0.z + w1 * (float)g1.z + w2 * (float)g2.z + w3 * (float)g3.z
                    + w4 * (float)g4v.z + w5 * (float)g5v.z + w6 * (float)g6.z + w7 * (float)g7.z;
        aw = aw * c + w0 * (float)g0.w + w1 * (float)g1.w + w2 * (float)g2.w + w3 * (float)g3.w
                    + w4 * (float)g4v.w + w5 * (float)g5v.w + w6 * (float)g6.w + w7 * (float)g7.w;
        m = mn;
    }
    for (; k + 3 < s1; k += 4) {
        int i0 = col[k], i1 = col[k + 1], i2 = col[k + 2], i3 = col[k + 3];
        float e0 = lrelu(a_s[i0 * 4 + hh] + adsel);
        float e1 = lrelu(a_s[i1 * 4 + hh] + adsel);
        float e2 = lrelu(a_s[i2 * 4 + hh] + adsel);
        float e3 = lrelu(a_s[i3 * 4 + hh] + adsel);
        half4 g0 = gv4[(size_t)i0 * 64 + lane];
        half4 g1 = gv4[(size_t)i1 * 64 + lane];
        half4 g2 = gv4[(size_t)i2 * 64 + lane];
        half4 g3 = gv4[(size_t)i3 * 64 + lane];
        float mn = fmaxf(fmaxf(fmaxf(e0, e1), fmaxf(e2, e3)), m);
        float c = __expf(m - mn);
        float w0 = __expf(e0 - mn), w1 = __expf(e1 - mn);
        float w2 = __expf(e2 - mn), w3 = __expf(e3 - mn);
        t = t * c + (w0 + w1) + (w2 + w3);
        ax = ax * c + w0 * (float)g0.x + w1 * (float)g1.x + w2 * (float)g2.x + w3 * (float)g3.x;
        ay = ay * c + w0 * (float)g0.y + w1 * (float)g1.y + w2 * (float)g2.y + w3 * (float)g3.y;
        az = az * c + w0 * (float)g0.z + w1 * (float)g1.z + w2 * (float)g2.z + w3 * (float)g3.z;
        aw = aw * c + w0 * (float)g0.w + w1 * (float)g1.w + w2 * (float)g2.w + w3 * (float)g3.w;
        m = mn;
    }
    for (; k < s1; ++k) {
        int s = col[k];
        float e = lrelu(a_s[s * 4 + hh] + adsel);
        half4 gv = gv4[(size_t)s * 64 + lane];
        float mn = fmaxf(m, e);
        float c = __expf(m - mn);
        float w = __expf(e - mn);
        t = t * c + w;
        ax = ax * c + w * (float)gv.x;
        ay = ay * c + w * (float)gv.y;
        az = az * c + w * (float)gv.z;
        aw = aw * c + w * (float)gv.w;
        m = mn;
    }
    float r = 1.f / t;

    float4 gb = ((const float4*)gat_b)[lane];
    float zx = fmaxf(ax * r + gb.x, 0.f);
    float zy = fmaxf(ay * r + gb.y, 0.f);
    float zz = fmaxf(az * r + gb.z, 0.f);
    float zw = fmaxf(aw * r + gb.w, 0.f);

    int b = batch[wid];
    if (lane == 0) bids[wv] = b;
    zpool[tid] = 0.f;
    __syncthreads();
    bool uni = (bids[0] == bids[1]) && (bids[1] == bids[2]) && (bids[2] == bids[3]);
    if (uni) {
        atomicAdd(&zpool[lane * 4 + 0], zx);
        atomicAdd(&zpool[lane * 4 + 1], zy);
        atomicAdd(&zpool[lane * 4 + 2], zz);
        atomicAdd(&zpool[lane * 4 + 3], zw);
        __syncthreads();
        if (wv == 0) {
            float* p = pool + (size_t)bids[0] * 256;
            atomicAdd(&p[lane * 4 + 0], zpool[lane * 4 + 0]);
            atomicAdd(&p[lane * 4 + 1], zpool[lane * 4 + 1]);
            atomicAdd(&p[lane * 4 + 2], zpool[lane * 4 + 2]);
            atomicAdd(&p[lane * 4 + 3], zpool[lane * 4 + 3]);
        }
        if (tid == 0) atomicAdd(&cnt_g[bids[0]], 4.0f);
    } else {
        __syncthreads();
        float* p = pool + (size_t)b * 256;
        atomicAdd(&p[lane * 4 + 0], zx);
        atomicAdd(&p[lane * 4 + 1], zy);
        atomicAdd(&p[lane * 4 + 2], zz);
        atomicAdd(&p[lane * 4 + 3], zw);
        if (lane == 0) atomicAdd(&cnt_g[b], 1.0f);
    }
}

// ---------------- output projection ----------------

__global__ void k_out(const float* __restrict__ pool, const float* __restrict__ cnt_g,
                      const float* __restrict__ W, const float* __restrict__ b,
                      float* __restrict__ out) {
    int idx = blockIdx.x * blockDim.x + threadIdx.x;
    if (idx >= NGRAPH * NOUT) return;
    int gg = idx >> 5, o = idx & 31;
    float c = cnt_g[gg];
    c = c > 1.f ? c : 1.f;
    float rinv = 1.f / c;
    const float* p = pool + (size_t)gg * 256;
    float acc = 0.f;
#pragma unroll 8
    for (int f = 0; f < 256; ++f) acc += p[f] * W[f * 32 + o];
    out[idx] = acc * rinv + b[o];
}

// ---------------- launch ----------------

extern "C" void kernel_launch(void* const* d_in, const int* in_sizes, int n_in,
                              void* d_out, int out_size, void* d_ws, size_t ws_size,
                              hipStream_t stream) {
    const float* x       = (const float*)d_in[0];
    const int*   eidx    = (const int*)d_in[1];
    const int*   batch   = (const int*)d_in[2];
    const float* gcn_W   = (const float*)d_in[3];
    const float* gcn_b   = (const float*)d_in[4];
    const float* gat_W   = (const float*)d_in[5];
    const float* att_src = (const float*)d_in[6];
    const float* att_dst = (const float*)d_in[7];
    const float* gat_b   = (const float*)d_in[8];
    const float* out_W   = (const float*)d_in[9];
    const float* out_b   = (const float*)d_in[10];
    float* out = (float*)d_out;

    const int* src = eidx;        // edge_index[0]
    const int* dst = eidx + NE;   // edge_index[1]

    size_t off = 0;
    auto carve = [&](size_t bytes) -> char* {
        char* p = (char*)d_ws + off;
        off += (bytes + 255) & ~(size_t)255;
        return p;
    };
    int*      cnt     = (int*)carve(NN * sizeof(int));
    int*      pos     = (int*)carve((size_t)NE * sizeof(int));
    int*      row_ptr = (int*)carve((NN + 1) * sizeof(int));
    int*      bsum    = (int*)carve(256 * sizeof(int));
    int*      colb    = (int*)carve((size_t)NEP * sizeof(int));
    float*    dinv    = (float*)carve(NN * sizeof(float));
    _Float16* hx16    = (_Float16*)carve((size_t)NN * 64 * sizeof(_Float16));
    _Float16* h16     = (_Float16*)carve((size_t)NN * 64 * sizeof(_Float16));
    _Float16* g16     = (_Float16*)carve((size_t)NN * 256 * sizeof(_Float16));
    float*    a_s     = (float*)carve((size_t)NN * 4 * sizeof(float));
    float*    a_d     = (float*)carve((size_t)NN * 4 * sizeof(float));
    float*    pool    = (float*)carve((size_t)NGRAPH * 256 * sizeof(float));
    float*    cnt_g   = (float*)carve(NGRAPH * sizeof(float));

    hipMemsetAsync(cnt, 0, NN * sizeof(int), stream);

    // CSR build: 1 atomic per edge total (k_count records slot), k_fill atomic-free
    k_count<<<(NE + 255) / 256, 256, 0, stream>>>(dst, cnt, pos);
    k_scan1<<<NBLK, 256, 0, stream>>>(cnt, bsum, pool, cnt_g);
    k_scan3<<<NBLK, 256, 0, stream>>>(cnt, bsum, row_ptr, dinv, colb);
    k_fill<<<(NE + 255) / 256, 256, 0, stream>>>(src, dst, row_ptr, pos, colb);

    // GCN
    k_gemm64<<<(NN + 63) / 64, 256, 0, stream>>>(x, gcn_W, hx16, NN);
    k_gcn_agg<<<(NN * 64 + 255) / 256, 256, 0, stream>>>(hx16, row_ptr, colb, dinv, gcn_b, h16);

    // GAT (gemm + fused logits -> fp16 g, then single-pass online softmax agg)
    k_gemm256<<<(NN + 31) / 32, 256, 0, stream>>>(h16, gat_W, att_src, att_dst, g16, a_s, a_d);
    k_gat<<<NN / 4, 256, 0, stream>>>(g16, a_s, a_d, row_ptr, colb, gat_b, batch, pool, cnt_g);

    // output projection
    k_out<<<(NGRAPH * NOUT + 255) / 256, 256, 0, stream>>>(pool, cnt_g, out_W, out_b, out);
}